// Round 1
// baseline (111.656 us; speedup 1.0000x reference)
//
#include <hip/hip_runtime.h>

#define NN   1024
#define INF  21
#define EE   128
#define NB   65   // 2*BINS+1
#define BINSV 32

// Kernel 1: a = tf @ Wa^T + ba ; b = tf @ Wb^T + bb   (both [N, E])
__global__ __launch_bounds__(128) void proj_kernel(
    const float* __restrict__ tf,
    const float* __restrict__ Wa, const float* __restrict__ ba,
    const float* __restrict__ Wb, const float* __restrict__ bb,
    float* __restrict__ a, float* __restrict__ b) {
  int i = blockIdx.x;        // row of target_feat
  int e = threadIdx.x;       // 0..127 output feature
  __shared__ float row[INF];
  if (e < INF) row[e] = tf[i * INF + e];
  __syncthreads();
  float sa = ba[e];
  float sb = bb[e];
#pragma unroll
  for (int k = 0; k < INF; ++k) {
    float r = row[k];
    sa = fmaf(r, Wa[e * INF + k], sa);
    sb = fmaf(r, Wb[e * INF + k], sb);
  }
  a[i * EE + e] = sa;
  b[i * EE + e] = sb;
}

// Kernel 2: ptab[d][e] = Wp[e][d] + bp[e]   (Wp is [E, 65] row-major)
__global__ __launch_bounds__(128) void ptab_kernel(
    const float* __restrict__ Wp, const float* __restrict__ bp,
    float* __restrict__ ptab) {
  int d = blockIdx.x;        // 0..64
  int e = threadIdx.x;       // 0..127
  ptab[d * EE + e] = Wp[e * NB + d] + bp[e];
}

// Kernel 3: out[i][j][e] = a[i][e] + b[j][e] + ptab[clip(ri[i]-ri[j])][e]
// One block per i. 512 threads: 16 j-groups x 32 float4-lanes (E=128 -> 32 float4).
__global__ __launch_bounds__(512) void fill_kernel(
    const float* __restrict__ a, const float* __restrict__ b,
    const float* __restrict__ ptab, const int* __restrict__ ri,
    float* __restrict__ out) {
  __shared__ int sri[NN];
  for (int t = threadIdx.x; t < NN; t += 512) sri[t] = ri[t];
  __syncthreads();

  const int i  = blockIdx.x;
  const int e4 = threadIdx.x & 31;   // float4 index within E
  const int jg = threadIdx.x >> 5;   // 0..15

  const float4 av = reinterpret_cast<const float4*>(a + i * EE)[e4];
  const int rii = sri[i];
  float4* outrow = reinterpret_cast<float4*>(out + (size_t)i * NN * EE);

  for (int j = jg; j < NN; j += 16) {
    int d = rii - sri[j];
    d = (d < -BINSV) ? -BINSV : (d > BINSV ? BINSV : d);
    d += BINSV;
    const float4 bv = reinterpret_cast<const float4*>(b + j * EE)[e4];
    const float4 pv = reinterpret_cast<const float4*>(ptab + d * EE)[e4];
    float4 o;
    o.x = av.x + bv.x + pv.x;
    o.y = av.y + bv.y + pv.y;
    o.z = av.z + bv.z + pv.z;
    o.w = av.w + bv.w + pv.w;
    outrow[j * 32 + e4] = o;
  }
}

extern "C" void kernel_launch(void* const* d_in, const int* in_sizes, int n_in,
                              void* d_out, int out_size, void* d_ws, size_t ws_size,
                              hipStream_t stream) {
  const float* tf = (const float*)d_in[0];
  const int*   ri = (const int*)d_in[1];
  const float* Wa = (const float*)d_in[2];
  const float* ba = (const float*)d_in[3];
  const float* Wb = (const float*)d_in[4];
  const float* bb = (const float*)d_in[5];
  const float* Wp = (const float*)d_in[6];
  const float* bp = (const float*)d_in[7];
  float* out = (float*)d_out;

  float* ws   = (float*)d_ws;
  float* a    = ws;                 // N*E floats
  float* b    = ws + NN * EE;       // N*E floats
  float* ptab = ws + 2 * NN * EE;   // 65*E floats

  proj_kernel<<<NN, 128, 0, stream>>>(tf, Wa, ba, Wb, bb, a, b);
  ptab_kernel<<<NB, 128, 0, stream>>>(Wp, bp, ptab);
  fill_kernel<<<NN, 512, 0, stream>>>(a, b, ptab, ri, out);
}

// Round 3
// 109.828 us; speedup vs baseline: 1.0166x; 1.0166x over previous
//
#include <hip/hip_runtime.h>

#define NN   1024
#define INF  21
#define EE   128
#define NB   65   // 2*BINS+1
#define BINSV 32

typedef float f32x4 __attribute__((ext_vector_type(4)));

// Kernel 1 (merged): blocks [0, NN) do the two linear projections;
// blocks [NN, NN+NB) build ptab[d][e] = Wp[e][d] + bp[e].
__global__ __launch_bounds__(128) void prep_kernel(
    const float* __restrict__ tf,
    const float* __restrict__ Wa, const float* __restrict__ ba,
    const float* __restrict__ Wb, const float* __restrict__ bb,
    const float* __restrict__ Wp, const float* __restrict__ bp,
    float* __restrict__ a, float* __restrict__ b, float* __restrict__ ptab) {
  const int e = threadIdx.x;  // 0..127
  if (blockIdx.x < NN) {
    const int i = blockIdx.x;
    __shared__ float row[INF];
    if (e < INF) row[e] = tf[i * INF + e];
    __syncthreads();
    float sa = ba[e];
    float sb = bb[e];
#pragma unroll
    for (int k = 0; k < INF; ++k) {
      float r = row[k];
      sa = fmaf(r, Wa[e * INF + k], sa);
      sb = fmaf(r, Wb[e * INF + k], sb);
    }
    a[i * EE + e] = sa;
    b[i * EE + e] = sb;
  } else {
    const int d = blockIdx.x - NN;  // 0..64
    ptab[d * EE + e] = Wp[e * NB + d] + bp[e];
  }
}

// Kernel 2: out[i][j][e] = a[i][e] + b[j][e] + ptab[clip(ri[i]-ri[j])][e]
// One block per i. 512 threads: 16 j-groups x 32 f32x4-lanes.
// Software-pipelined (load j+16 while storing j) + nontemporal stores.
__global__ __launch_bounds__(512) void fill_kernel(
    const float* __restrict__ a, const float* __restrict__ b,
    const float* __restrict__ ptab, const int* __restrict__ ri,
    float* __restrict__ out) {
  __shared__ int sri[NN];
  for (int t = threadIdx.x; t < NN; t += 512) sri[t] = ri[t];
  __syncthreads();

  const int i  = blockIdx.x;
  const int e4 = threadIdx.x & 31;   // f32x4 index within E
  const int jg = threadIdx.x >> 5;   // 0..15

  const f32x4* __restrict__ b4 = reinterpret_cast<const f32x4*>(b);
  const f32x4* __restrict__ p4 = reinterpret_cast<const f32x4*>(ptab);

  const f32x4 av = reinterpret_cast<const f32x4*>(a + i * EE)[e4];
  const int rii = sri[i];
  f32x4* outrow = reinterpret_cast<f32x4*>(out + (size_t)i * NN * EE);

  auto bin = [&](int j) {
    int d = rii - sri[j];
    d = (d < -BINSV) ? -BINSV : (d > BINSV ? BINSV : d);
    return d + BINSV;
  };

  // prologue: load iteration jg
  int j = jg;
  f32x4 bv = b4[j * 32 + e4];
  f32x4 pv = p4[bin(j) * 32 + e4];

  for (int jn = jg + 16; jn < NN; jn += 16) {
    // prefetch next iteration's operands before the store
    f32x4 bvn = b4[jn * 32 + e4];
    f32x4 pvn = p4[bin(jn) * 32 + e4];
    f32x4 o = av + bv + pv;
    __builtin_nontemporal_store(o, outrow + j * 32 + e4);
    j = jn; bv = bvn; pv = pvn;
  }
  // epilogue
  f32x4 o = av + bv + pv;
  __builtin_nontemporal_store(o, outrow + j * 32 + e4);
}

extern "C" void kernel_launch(void* const* d_in, const int* in_sizes, int n_in,
                              void* d_out, int out_size, void* d_ws, size_t ws_size,
                              hipStream_t stream) {
  const float* tf = (const float*)d_in[0];
  const int*   ri = (const int*)d_in[1];
  const float* Wa = (const float*)d_in[2];
  const float* ba = (const float*)d_in[3];
  const float* Wb = (const float*)d_in[4];
  const float* bb = (const float*)d_in[5];
  const float* Wp = (const float*)d_in[6];
  const float* bp = (const float*)d_in[7];
  float* out = (float*)d_out;

  float* ws   = (float*)d_ws;
  float* a    = ws;                 // N*E floats
  float* b    = ws + NN * EE;       // N*E floats
  float* ptab = ws + 2 * NN * EE;   // 65*E floats

  prep_kernel<<<NN + NB, 128, 0, stream>>>(tf, Wa, ba, Wb, bb, Wp, bp, a, b, ptab);
  fill_kernel<<<NN, 512, 0, stream>>>(a, b, ptab, ri, out);
}